// Round 1
// baseline (947.253 us; speedup 1.0000x reference)
//
#include <hip/hip_runtime.h>

// ConvLSTM fp32 reference-faithful implementation, round 0 (correctness-first).
// Shapes: NB=2 (N*C), S=7 (5 code + 2 ncode), VOX=512 (8^3), H=64, 4H=256, VOC=512, L=2.

#define WSTRIDE 442368   // per-layer conv weight elements: 27*64*256

__device__ __forceinline__ float wred_sum(float v) {
    #pragma unroll
    for (int o = 32; o > 0; o >>= 1) v += __shfl_down(v, o, 64);
    return __shfl(v, 0, 64);
}

// h[nc][s][vox][ch] = emb[tok][ch]
__global__ __launch_bounds__(256) void embed_kernel(
    const int* __restrict__ code, const int* __restrict__ ncode,
    const float* __restrict__ emb, float* __restrict__ h)
{
    int e = blockIdx.x * 256 + threadIdx.x;   // < 2*7*512*64 = 458752
    int ch = e & 63;
    int pos = e >> 6;            // nc*7*512 + s*512 + vox
    int vox = pos & 511;
    int t = pos >> 9;            // nc*7 + s
    int s = t % 7, nc = t / 7;
    int tok = (s < 5) ? code[(nc*5 + s)*512 + vox]
                      : ncode[(nc*3 + (s-5))*512 + vox];
    h[e] = emb[tok*64 + ch];
}

// Generic 3x3x3 SAME conv, Cin=64 -> Cout=256, raw output + bias.
// x: [nslabs][512][64], wt: [27][64][256], y: [nslabs][512][256]
// grid = nslabs*8*4 blocks; block computes (u-plane 64 voxels) x (64 couts).
// thread = (co quad t&15, 2x2 voxel patch t>>4); acc[4 co][4 vox].
__global__ __launch_bounds__(256) void conv_kernel(
    const float* __restrict__ x, const float* __restrict__ wt,
    const float* __restrict__ bias, float* __restrict__ y)
{
    __shared__ float xs[3][64][65];    // [du][ci][vox(v*8+w)], pad 65 to break write conflicts
    const int b = blockIdx.x;
    const int cg   = b & 3;
    const int u    = (b >> 2) & 7;
    const int slab = b >> 5;
    const int t = threadIdx.x;

    #pragma unroll
    for (int du = 0; du < 3; ++du) {
        const int uu = u + du - 1;
        const bool ok = (uu >= 0) && (uu < 8);
        const float* xp = x + (size_t)(slab*512 + uu*64)*64;
        for (int p = 0; p < 16; ++p) {
            int idx = p*256 + t;               // vw*64 + ci
            xs[du][idx & 63][idx >> 6] = ok ? xp[idx] : 0.f;
        }
    }
    __syncthreads();

    const int co4 = t & 15, vg = t >> 4;
    const int co = cg*64 + co4*4;
    const int v0 = (vg >> 2) << 1;
    const int w0 = (vg & 3) << 1;

    int xoff[16];
    #pragma unroll
    for (int a = 0; a < 4; ++a)
        #pragma unroll
        for (int bb = 0; bb < 4; ++bb) {
            int vv = v0 - 1 + a, ww = w0 - 1 + bb;
            xoff[a*4+bb] = (vv >= 0 && vv < 8 && ww >= 0 && ww < 8) ? (vv*8 + ww) : -1;
        }

    float acc[4][4] = {};
    for (int du = 0; du < 3; ++du) {
        for (int ci = 0; ci < 64; ++ci) {
            float xpv[16];
            #pragma unroll
            for (int q = 0; q < 16; ++q)
                xpv[q] = (xoff[q] >= 0) ? xs[du][ci][xoff[q]] : 0.f;
            #pragma unroll
            for (int dv = 0; dv < 3; ++dv)
                #pragma unroll
                for (int dw = 0; dw < 3; ++dw) {
                    const float4 wv = *(const float4*)(wt + (size_t)((((du*3+dv)*3+dw)*64 + ci)*256 + co));
                    #pragma unroll
                    for (int j = 0; j < 4; ++j) {
                        float xv = xpv[((j>>1)+dv)*4 + ((j&1)+dw)];
                        acc[0][j] = fmaf(wv.x, xv, acc[0][j]);
                        acc[1][j] = fmaf(wv.y, xv, acc[1][j]);
                        acc[2][j] = fmaf(wv.z, xv, acc[2][j]);
                        acc[3][j] = fmaf(wv.w, xv, acc[3][j]);
                    }
                }
        }
    }
    const float4 bv = *(const float4*)(bias + co);
    #pragma unroll
    for (int j = 0; j < 4; ++j) {
        int v = v0 + (j>>1), w = w0 + (j&1);
        float4 o;
        o.x = acc[0][j] + bv.x; o.y = acc[1][j] + bv.y;
        o.z = acc[2][j] + bv.z; o.w = acc[3][j] + bv.w;
        *(float4*)(y + (size_t)((slab*512 + u*64 + v*8 + w)*256 + co)) = o;
    }
}

// Recurrent conv variant: tiny batch (2 slabs), so split cout into 16 groups
// and split K (ci) 4-way across the block with an LDS reduction -> 256 blocks.
__global__ __launch_bounds__(256) void conv_rec_kernel(
    const float* __restrict__ x, const float* __restrict__ wt,
    const float* __restrict__ bias, float* __restrict__ y)
{
    __shared__ float xs[3][64][65];
    const int b = blockIdx.x;          // 2*8*16 = 256
    const int cg   = b & 15;
    const int u    = (b >> 4) & 7;
    const int slab = b >> 7;
    const int t = threadIdx.x;

    #pragma unroll
    for (int du = 0; du < 3; ++du) {
        const int uu = u + du - 1;
        const bool ok = (uu >= 0) && (uu < 8);
        const float* xp = x + (size_t)(slab*512 + uu*64)*64;
        for (int p = 0; p < 16; ++p) {
            int idx = p*256 + t;
            xs[du][idx & 63][idx >> 6] = ok ? xp[idx] : 0.f;
        }
    }
    __syncthreads();

    const int kp = t >> 6;             // ci quarter
    const int lane = t & 63;
    const int coq = lane & 3, vg = lane >> 2;
    const int co = cg*16 + coq*4;
    const int v0 = (vg >> 2) << 1;
    const int w0 = (vg & 3) << 1;

    int xoff[16];
    #pragma unroll
    for (int a = 0; a < 4; ++a)
        #pragma unroll
        for (int bb = 0; bb < 4; ++bb) {
            int vv = v0 - 1 + a, ww = w0 - 1 + bb;
            xoff[a*4+bb] = (vv >= 0 && vv < 8 && ww >= 0 && ww < 8) ? (vv*8 + ww) : -1;
        }

    float acc[4][4] = {};
    const int ci0 = kp * 16;
    for (int du = 0; du < 3; ++du) {
        for (int cii = 0; cii < 16; ++cii) {
            const int ci = ci0 + cii;
            float xpv[16];
            #pragma unroll
            for (int q = 0; q < 16; ++q)
                xpv[q] = (xoff[q] >= 0) ? xs[du][ci][xoff[q]] : 0.f;
            #pragma unroll
            for (int dv = 0; dv < 3; ++dv)
                #pragma unroll
                for (int dw = 0; dw < 3; ++dw) {
                    const float4 wv = *(const float4*)(wt + (size_t)((((du*3+dv)*3+dw)*64 + ci)*256 + co));
                    #pragma unroll
                    for (int j = 0; j < 4; ++j) {
                        float xv = xpv[((j>>1)+dv)*4 + ((j&1)+dw)];
                        acc[0][j] = fmaf(wv.x, xv, acc[0][j]);
                        acc[1][j] = fmaf(wv.y, xv, acc[1][j]);
                        acc[2][j] = fmaf(wv.z, xv, acc[2][j]);
                        acc[3][j] = fmaf(wv.w, xv, acc[3][j]);
                    }
                }
        }
    }
    __syncthreads();                    // done reading xs, reuse as reduction buffer
    float* red = &xs[0][0][0];          // need 16*256 = 4096 floats, xs has 12480
    #pragma unroll
    for (int a = 0; a < 4; ++a)
        #pragma unroll
        for (int j = 0; j < 4; ++j)
            red[(a*4+j)*256 + t] = acc[a][j];
    __syncthreads();
    if (t < 64) {                       // kp==0 class owns the final sum
        const float4 bv = *(const float4*)(bias + co);
        float fin[16];
        #pragma unroll
        for (int i = 0; i < 16; ++i)
            fin[i] = red[i*256 + t] + red[i*256 + 64 + t]
                   + red[i*256 + 128 + t] + red[i*256 + 192 + t];
        #pragma unroll
        for (int j = 0; j < 4; ++j) {
            int v = v0 + (j>>1), w = w0 + (j&1);
            float4 o;
            o.x = fin[0*4+j] + bv.x; o.y = fin[1*4+j] + bv.y;
            o.z = fin[2*4+j] + bv.z; o.w = fin[3*4+j] + bv.w;
            *(float4*)(y + (size_t)((slab*512 + u*64 + v*8 + w)*256 + co)) = o;
        }
    }
}

// In-place LayerNorm over 256 channels, one wave per row (4 rows/block).
__global__ __launch_bounds__(256) void ln_kernel(
    float* __restrict__ yio, const float* __restrict__ g,
    const float* __restrict__ b)
{
    const int wid = threadIdx.x >> 6, lane = threadIdx.x & 63;
    const int row = blockIdx.x * 4 + wid;
    float4 v = *(const float4*)(yio + (size_t)row*256 + lane*4);
    float mu = wred_sum(v.x + v.y + v.z + v.w) * (1.f/256.f);
    float4 d = { v.x-mu, v.y-mu, v.z-mu, v.w-mu };
    float var = wred_sum(d.x*d.x + d.y*d.y + d.z*d.z + d.w*d.w) * (1.f/256.f);
    float rs = rsqrtf(var + 1e-5f);
    float4 gv = *(const float4*)(g + lane*4);
    float4 bv = *(const float4*)(b + lane*4);
    float4 o = { d.x*rs*gv.x + bv.x, d.y*rs*gv.y + bv.y,
                 d.z*rs*gv.z + bv.z, d.w*rs*gv.w + bv.w };
    *(float4*)(yio + (size_t)row*256 + lane*4) = o;
}

// LSTM cell: LN(ghat) + gi -> gates -> update cx, hx; also store hx into h[nc][s].
// One wave per (nc,vox) row; lane = channel.
__global__ __launch_bounds__(256) void gates_kernel(
    const float* __restrict__ ghat,   // [2*512][256]
    const float* __restrict__ gi,     // [nc][7][512][256]
    const float* __restrict__ gg, const float* __restrict__ gb,
    float* __restrict__ hx, float* __restrict__ cx,
    float* __restrict__ h, int s)
{
    const int wid = threadIdx.x >> 6, lane = threadIdx.x & 63;
    const int row = blockIdx.x * 4 + wid;     // nc*512 + vox, < 1024
    const int nc = row >> 9, vox = row & 511;
    const float* gr = ghat + (size_t)row*256;
    float xi = gr[lane], xf = gr[64+lane], xc = gr[128+lane], xo = gr[192+lane];
    float mu = wred_sum(xi + xf + xc + xo) * (1.f/256.f);
    float di = xi-mu, df = xf-mu, dc = xc-mu, dq = xo-mu;
    float var = wred_sum(di*di + df*df + dc*dc + dq*dq) * (1.f/256.f);
    float rs = rsqrtf(var + 1e-5f);
    const float* gir = gi + (size_t)((nc*7 + s)*512 + vox)*256;
    float Ig = gir[lane]     + di*rs*gg[lane]     + gb[lane];
    float Fg = gir[64+lane]  + df*rs*gg[64+lane]  + gb[64+lane];
    float Cg = gir[128+lane] + dc*rs*gg[128+lane] + gb[128+lane];
    float Og = gir[192+lane] + dq*rs*gg[192+lane] + gb[192+lane];
    float c_old = cx[(size_t)row*64 + lane];
    float c_new = (1.f/(1.f+expf(-Fg))) * c_old + (1.f/(1.f+expf(-Ig))) * tanhf(Cg);
    float h_new = (1.f/(1.f+expf(-Og))) * tanhf(c_new);
    cx[(size_t)row*64 + lane] = c_new;
    hx[(size_t)row*64 + lane] = h_new;
    h[(size_t)((nc*7 + s)*512 + vox)*64 + lane] = h_new;
}

// Head: per (n,sn,vox) row: y=h@w1+b1 -> LN -> gelu(exact) -> logits=z@w2+b2
// -> score (transposed write), log_softmax target -> loss atomic, argmax -> pred.
__global__ __launch_bounds__(256) void head_kernel(
    const float* __restrict__ h,      // [2][7][512][64]
    const float* __restrict__ w1, const float* __restrict__ b1,
    const float* __restrict__ lng, const float* __restrict__ lnb,
    const float* __restrict__ w2, const float* __restrict__ b2,
    const int* __restrict__ ncode,
    float* __restrict__ out)
{
    __shared__ float zv[64];
    __shared__ float lg[512];
    __shared__ float smax[256];
    __shared__ int   sidx[256];
    __shared__ float ssum[256];
    const int r = blockIdx.x;                  // (n*3+sn)*512 + vox
    const int n = r / 1536, rem = r % 1536;
    const int sn = rem >> 9, vox = rem & 511;
    const int t = threadIdx.x;
    const int s = sn + 4;                      // h[:, -3:]
    const float* hv = h + (size_t)((n*7 + s)*512 + vox)*64;

    if (t < 64) {
        float y = b1[t];
        for (int k = 0; k < 64; ++k) y = fmaf(hv[k], w1[k*64 + t], y);
        float mu = wred_sum(y) * (1.f/64.f);
        float d = y - mu;
        float var = wred_sum(d*d) * (1.f/64.f);
        float ln = d * rsqrtf(var + 1e-5f) * lng[t] + lnb[t];
        zv[t] = 0.5f * ln * (1.f + erff(ln * 0.70710678118654752f));
    }
    __syncthreads();

    float l0 = b2[t], l1 = b2[t + 256];
    for (int k = 0; k < 64; ++k) {
        float zz = zv[k];
        l0 = fmaf(zz, w2[k*512 + t],       l0);
        l1 = fmaf(zz, w2[k*512 + t + 256], l1);
    }
    lg[t] = l0; lg[t + 256] = l1;
    out[(size_t)((n*512 + t)*3 + sn)*512 + vox]       = l0;
    out[(size_t)((n*512 + t + 256)*3 + sn)*512 + vox] = l1;

    float m; int mi;
    if (l0 >= l1) { m = l0; mi = t; } else { m = l1; mi = t + 256; }  // lower idx on tie
    smax[t] = m; sidx[t] = mi;
    __syncthreads();
    for (int off = 128; off > 0; off >>= 1) {
        if (t < off) {
            float om = smax[t + off]; int oi = sidx[t + off];
            if (om > smax[t] || (om == smax[t] && oi < sidx[t])) { smax[t] = om; sidx[t] = oi; }
        }
        __syncthreads();
    }
    const float maxv = smax[0];
    ssum[t] = expf(l0 - maxv) + expf(l1 - maxv);
    __syncthreads();
    for (int off = 128; off > 0; off >>= 1) {
        if (t < off) ssum[t] += ssum[t + off];
        __syncthreads();
    }
    if (t == 0) {
        int target = ncode[(n*3 + sn)*512 + vox];
        float logp = lg[target] - maxv - logf(ssum[0]);
        atomicAdd(out + 1572864, -logp * (1.f/3072.f));
        out[1572865 + r] = (float)sidx[0];
    }
}

extern "C" void kernel_launch(void* const* d_in, const int* in_sizes, int n_in,
                              void* d_out, int out_size, void* d_ws, size_t ws_size,
                              hipStream_t stream) {
    (void)in_sizes; (void)n_in; (void)out_size; (void)ws_size;
    const int*   code  = (const int*)d_in[0];
    const int*   ncode = (const int*)d_in[1];
    const float* emb   = (const float*)d_in[2];
    const float* win   = (const float*)d_in[3];
    const float* bin_  = (const float*)d_in[4];
    const float* gin_w = (const float*)d_in[5];
    const float* gin_b = (const float*)d_in[6];
    const float* wh    = (const float*)d_in[7];
    const float* bh    = (const float*)d_in[8];
    const float* gh_w  = (const float*)d_in[9];
    const float* gh_b  = (const float*)d_in[10];
    const float* w1    = (const float*)d_in[11];
    const float* b1    = (const float*)d_in[12];
    const float* ln_g  = (const float*)d_in[13];
    const float* ln_b  = (const float*)d_in[14];
    const float* w2    = (const float*)d_in[15];
    const float* b2    = (const float*)d_in[16];
    float* out = (float*)d_out;

    float* h    = (float*)d_ws;        // [2][7][512][64]   = 458752
    float* gi   = h + 458752;          // [2][7][512][256]  = 1835008
    float* ghat = gi + 1835008;        // [2][512][256]     = 262144
    float* hx   = ghat + 262144;       // [2][512][64]      = 65536
    float* cx   = hx + 65536;          // [2][512][64]      = 65536

    hipMemsetAsync(out + 1572864, 0, sizeof(float), stream);   // loss accumulator
    embed_kernel<<<1792, 256, 0, stream>>>(code, ncode, emb, h);

    for (int l = 0; l < 2; ++l) {
        // input-path conv over all 14 slabs, then LN in-place -> gi
        conv_kernel<<<14*32, 256, 0, stream>>>(h, win + l*WSTRIDE, bin_ + l*256, gi);
        ln_kernel<<<1792, 256, 0, stream>>>(gi, gin_w + l*256, gin_b + l*256);
        hipMemsetAsync(hx, 0, 65536*sizeof(float), stream);
        hipMemsetAsync(cx, 0, 65536*sizeof(float), stream);
        for (int s = 0; s < 7; ++s) {
            conv_rec_kernel<<<256, 256, 0, stream>>>(hx, wh + l*WSTRIDE, bh + l*256, ghat);
            gates_kernel<<<256, 256, 0, stream>>>(ghat, gi, gh_w + l*256, gh_b + l*256,
                                                  hx, cx, h, s);
        }
    }
    head_kernel<<<3072, 256, 0, stream>>>(h, w1, b1, ln_g, ln_b, w2, b2, ncode, out);
}

// Round 2
// 887.481 us; speedup vs baseline: 1.0674x; 1.0674x over previous
//
#include <hip/hip_runtime.h>

// ConvLSTM fp32, round 2: LDS-staged weights in both conv kernels (kills the
// 16x-redundant L2 weight traffic that capped round 1 at 43% VALUBusy), plus
// a reworked head (4 vox/block, coalesced float4 score writes).

#define WSTRIDE 442368   // per-layer conv weight elements: 27*64*256

__device__ __forceinline__ float wred_sum(float v) {
    #pragma unroll
    for (int o = 32; o > 0; o >>= 1) v += __shfl_down(v, o, 64);
    return __shfl(v, 0, 64);
}

// h[nc][s][vox][ch] = emb[tok][ch]
__global__ __launch_bounds__(256) void embed_kernel(
    const int* __restrict__ code, const int* __restrict__ ncode,
    const float* __restrict__ emb, float* __restrict__ h)
{
    int e = blockIdx.x * 256 + threadIdx.x;   // < 2*7*512*64 = 458752
    int ch = e & 63;
    int pos = e >> 6;            // nc*7*512 + s*512 + vox
    int vox = pos & 511;
    int t = pos >> 9;            // nc*7 + s
    int s = t % 7, nc = t / 7;
    int tok = (s < 5) ? code[(nc*5 + s)*512 + vox]
                      : ncode[(nc*3 + (s-5))*512 + vox];
    h[e] = emb[tok*64 + ch];
}

// 3x3x3 SAME conv, Cin=64 -> Cout=256, raw output + bias.
// x: [nslabs][512][64], wt: [27][64][256], y: [nslabs][512][256]
// grid = nslabs*8*4; block = (u-plane 64 vox) x (64 couts).
// Weights staged through LDS in (du, 8-ci) chunks: 16x less L2 traffic.
__global__ __launch_bounds__(256) void conv_kernel(
    const float* __restrict__ x, const float* __restrict__ wt,
    const float* __restrict__ bias, float* __restrict__ y)
{
    __shared__ float xs[3][64][65];                 // [du][ci][vox], ~49.9 KB
    __shared__ __align__(16) float ws[9][8][64];    // [tap][ci-in-chunk][co], 18 KB
    const int b = blockIdx.x;
    const int cg   = b & 3;
    const int u    = (b >> 2) & 7;
    const int slab = b >> 5;
    const int t = threadIdx.x;

    #pragma unroll
    for (int du = 0; du < 3; ++du) {
        const int uu = u + du - 1;
        const bool ok = (uu >= 0) && (uu < 8);
        const float* xp = x + (size_t)(slab*512 + uu*64)*64;
        for (int p = 0; p < 16; ++p) {
            int idx = p*256 + t;               // vw*64 + ci
            xs[du][idx & 63][idx >> 6] = ok ? xp[idx] : 0.f;
        }
    }

    const int co4 = t & 15, vg = t >> 4;
    const int co = cg*64 + co4*4;
    const int v0 = (vg >> 2) << 1;
    const int w0 = (vg & 3) << 1;

    int xoff[16];
    #pragma unroll
    for (int a = 0; a < 4; ++a)
        #pragma unroll
        for (int bb = 0; bb < 4; ++bb) {
            int vv = v0 - 1 + a, ww = w0 - 1 + bb;
            xoff[a*4+bb] = (vv >= 0 && vv < 8 && ww >= 0 && ww < 8) ? (vv*8 + ww) : -1;
        }

    float acc[4][4] = {};
    for (int du = 0; du < 3; ++du) {
        for (int c8 = 0; c8 < 8; ++c8) {
            __syncthreads();                     // xs ready / prev ws consumed
            // stage ws[9][8][64] = 1152 float4
            #pragma unroll
            for (int p = 0; p < 5; ++p) {
                int idx = p*256 + t;
                if (idx < 1152) {
                    int row = idx >> 4, f = idx & 15;
                    int tap = row >> 3, cii = row & 7;
                    int ci = c8*8 + cii;
                    float4 v = *(const float4*)(wt +
                        (size_t)(((du*9 + tap)*64 + ci)*256 + cg*64 + f*4));
                    *(float4*)&ws[tap][cii][f*4] = v;
                }
            }
            __syncthreads();
            for (int cii = 0; cii < 8; ++cii) {
                const int ci = c8*8 + cii;
                float xpv[16];
                #pragma unroll
                for (int q = 0; q < 16; ++q)
                    xpv[q] = (xoff[q] >= 0) ? xs[du][ci][xoff[q]] : 0.f;
                #pragma unroll
                for (int dv = 0; dv < 3; ++dv)
                    #pragma unroll
                    for (int dw = 0; dw < 3; ++dw) {
                        const float4 wv = *(const float4*)&ws[dv*3 + dw][cii][co4*4];
                        #pragma unroll
                        for (int j = 0; j < 4; ++j) {
                            float xv = xpv[((j>>1)+dv)*4 + ((j&1)+dw)];
                            acc[0][j] = fmaf(wv.x, xv, acc[0][j]);
                            acc[1][j] = fmaf(wv.y, xv, acc[1][j]);
                            acc[2][j] = fmaf(wv.z, xv, acc[2][j]);
                            acc[3][j] = fmaf(wv.w, xv, acc[3][j]);
                        }
                    }
            }
        }
    }
    const float4 bv = *(const float4*)(bias + co);
    #pragma unroll
    for (int j = 0; j < 4; ++j) {
        int v = v0 + (j>>1), w = w0 + (j&1);
        float4 o;
        o.x = acc[0][j] + bv.x; o.y = acc[1][j] + bv.y;
        o.z = acc[2][j] + bv.z; o.w = acc[3][j] + bv.w;
        *(float4*)(y + (size_t)((slab*512 + u*64 + v*8 + w)*256 + co)) = o;
    }
}

// Recurrent conv: 2 slabs only, so split cout into 16 groups and split K (ci)
// 4-way across the block with an LDS reduction -> 256 blocks. Weights staged
// through LDS in (du, half-of-each-quarter) chunks.
__global__ __launch_bounds__(256) void conv_rec_kernel(
    const float* __restrict__ x, const float* __restrict__ wt,
    const float* __restrict__ bias, float* __restrict__ y)
{
    __shared__ float xs[3][64][65];
    __shared__ __align__(16) float ws[9][4][8][16];  // [tap][kp][ci-in-chunk][co]
    const int b = blockIdx.x;          // 2*8*16 = 256
    const int cg   = b & 15;
    const int u    = (b >> 4) & 7;
    const int slab = b >> 7;
    const int t = threadIdx.x;

    #pragma unroll
    for (int du = 0; du < 3; ++du) {
        const int uu = u + du - 1;
        const bool ok = (uu >= 0) && (uu < 8);
        const float* xp = x + (size_t)(slab*512 + uu*64)*64;
        for (int p = 0; p < 16; ++p) {
            int idx = p*256 + t;
            xs[du][idx & 63][idx >> 6] = ok ? xp[idx] : 0.f;
        }
    }

    const int kp = t >> 6;             // ci quarter
    const int lane = t & 63;
    const int coq = lane & 3, vg = lane >> 2;
    const int co = cg*16 + coq*4;
    const int v0 = (vg >> 2) << 1;
    const int w0 = (vg & 3) << 1;

    int xoff[16];
    #pragma unroll
    for (int a = 0; a < 4; ++a)
        #pragma unroll
        for (int bb = 0; bb < 4; ++bb) {
            int vv = v0 - 1 + a, ww = w0 - 1 + bb;
            xoff[a*4+bb] = (vv >= 0 && vv < 8 && ww >= 0 && ww < 8) ? (vv*8 + ww) : -1;
        }

    float acc[4][4] = {};
    for (int du = 0; du < 3; ++du) {
        for (int c8 = 0; c8 < 2; ++c8) {
            __syncthreads();
            // stage ws[9][4][8][16] = 4608 floats = 1152 float4
            #pragma unroll
            for (int p = 0; p < 5; ++p) {
                int idx = p*256 + t;
                if (idx < 1152) {
                    int row = idx >> 2, f = idx & 3;
                    int tap = row >> 5, rem = row & 31;
                    int kpp = rem >> 3, cii = rem & 7;
                    int ci = kpp*16 + c8*8 + cii;
                    float4 v = *(const float4*)(wt +
                        (size_t)(((du*9 + tap)*64 + ci)*256 + cg*16 + f*4));
                    *(float4*)&ws[tap][kpp][cii][f*4] = v;
                }
            }
            __syncthreads();
            for (int cii = 0; cii < 8; ++cii) {
                const int ci = kp*16 + c8*8 + cii;
                float xpv[16];
                #pragma unroll
                for (int q = 0; q < 16; ++q)
                    xpv[q] = (xoff[q] >= 0) ? xs[du][ci][xoff[q]] : 0.f;
                #pragma unroll
                for (int dv = 0; dv < 3; ++dv)
                    #pragma unroll
                    for (int dw = 0; dw < 3; ++dw) {
                        const float4 wv = *(const float4*)&ws[dv*3 + dw][kp][cii][coq*4];
                        #pragma unroll
                        for (int j = 0; j < 4; ++j) {
                            float xv = xpv[((j>>1)+dv)*4 + ((j&1)+dw)];
                            acc[0][j] = fmaf(wv.x, xv, acc[0][j]);
                            acc[1][j] = fmaf(wv.y, xv, acc[1][j]);
                            acc[2][j] = fmaf(wv.z, xv, acc[2][j]);
                            acc[3][j] = fmaf(wv.w, xv, acc[3][j]);
                        }
                    }
            }
        }
    }
    __syncthreads();                    // done reading xs, reuse as reduction buffer
    float* red = &xs[0][0][0];          // need 16*256 = 4096 floats
    #pragma unroll
    for (int a = 0; a < 4; ++a)
        #pragma unroll
        for (int j = 0; j < 4; ++j)
            red[(a*4+j)*256 + t] = acc[a][j];
    __syncthreads();
    if (t < 64) {                       // kp==0 class owns the final sum
        const float4 bv = *(const float4*)(bias + co);
        float fin[16];
        #pragma unroll
        for (int i = 0; i < 16; ++i)
            fin[i] = red[i*256 + t] + red[i*256 + 64 + t]
                   + red[i*256 + 128 + t] + red[i*256 + 192 + t];
        #pragma unroll
        for (int j = 0; j < 4; ++j) {
            int v = v0 + (j>>1), w = w0 + (j&1);
            float4 o;
            o.x = fin[0*4+j] + bv.x; o.y = fin[1*4+j] + bv.y;
            o.z = fin[2*4+j] + bv.z; o.w = fin[3*4+j] + bv.w;
            *(float4*)(y + (size_t)((slab*512 + u*64 + v*8 + w)*256 + co)) = o;
        }
    }
}

// In-place LayerNorm over 256 channels, one wave per row (4 rows/block).
__global__ __launch_bounds__(256) void ln_kernel(
    float* __restrict__ yio, const float* __restrict__ g,
    const float* __restrict__ b)
{
    const int wid = threadIdx.x >> 6, lane = threadIdx.x & 63;
    const int row = blockIdx.x * 4 + wid;
    float4 v = *(const float4*)(yio + (size_t)row*256 + lane*4);
    float mu = wred_sum(v.x + v.y + v.z + v.w) * (1.f/256.f);
    float4 d = { v.x-mu, v.y-mu, v.z-mu, v.w-mu };
    float var = wred_sum(d.x*d.x + d.y*d.y + d.z*d.z + d.w*d.w) * (1.f/256.f);
    float rs = rsqrtf(var + 1e-5f);
    float4 gv = *(const float4*)(g + lane*4);
    float4 bv = *(const float4*)(b + lane*4);
    float4 o = { d.x*rs*gv.x + bv.x, d.y*rs*gv.y + bv.y,
                 d.z*rs*gv.z + bv.z, d.w*rs*gv.w + bv.w };
    *(float4*)(yio + (size_t)row*256 + lane*4) = o;
}

// LSTM cell: LN(ghat) + gi -> gates -> update cx, hx; store hx into h[nc][s].
__global__ __launch_bounds__(256) void gates_kernel(
    const float* __restrict__ ghat,   // [2*512][256]
    const float* __restrict__ gi,     // [nc][7][512][256]
    const float* __restrict__ gg, const float* __restrict__ gb,
    float* __restrict__ hx, float* __restrict__ cx,
    float* __restrict__ h, int s)
{
    const int wid = threadIdx.x >> 6, lane = threadIdx.x & 63;
    const int row = blockIdx.x * 4 + wid;     // nc*512 + vox, < 1024
    const int nc = row >> 9, vox = row & 511;
    const float* gr = ghat + (size_t)row*256;
    float xi = gr[lane], xf = gr[64+lane], xc = gr[128+lane], xo = gr[192+lane];
    float mu = wred_sum(xi + xf + xc + xo) * (1.f/256.f);
    float di = xi-mu, df = xf-mu, dc = xc-mu, dq = xo-mu;
    float var = wred_sum(di*di + df*df + dc*dc + dq*dq) * (1.f/256.f);
    float rs = rsqrtf(var + 1e-5f);
    const float* gir = gi + (size_t)((nc*7 + s)*512 + vox)*256;
    float Ig = gir[lane]     + di*rs*gg[lane]     + gb[lane];
    float Fg = gir[64+lane]  + df*rs*gg[64+lane]  + gb[64+lane];
    float Cg = gir[128+lane] + dc*rs*gg[128+lane] + gb[128+lane];
    float Og = gir[192+lane] + dq*rs*gg[192+lane] + gb[192+lane];
    float c_old = cx[(size_t)row*64 + lane];
    float c_new = (1.f/(1.f+expf(-Fg))) * c_old + (1.f/(1.f+expf(-Ig))) * tanhf(Cg);
    float h_new = (1.f/(1.f+expf(-Og))) * tanhf(c_new);
    cx[(size_t)row*64 + lane] = c_new;
    hx[(size_t)row*64 + lane] = h_new;
    h[(size_t)((nc*7 + s)*512 + vox)*64 + lane] = h_new;
}

// Head: 4 voxels per block, one wave per voxel.
// y=h@w1+b1 -> LN -> gelu -> logits=z@w2+b2 -> score (coalesced via LDS
// transpose), log_softmax target -> loss atomic, argmax -> pred.
__global__ __launch_bounds__(256) void head_kernel(
    const float* __restrict__ h,      // [2][7][512][64]
    const float* __restrict__ w1, const float* __restrict__ b1,
    const float* __restrict__ lng, const float* __restrict__ lnb,
    const float* __restrict__ w2, const float* __restrict__ b2,
    const int* __restrict__ ncode,
    float* __restrict__ out)
{
    __shared__ float zv[4][64];
    __shared__ float lg[4][512];
    const int blk = blockIdx.x;               // 768 = 2n * 3sn * 128 voxgroups
    const int n = blk / 384;
    const int sn = (blk / 128) % 3;
    const int vox0 = (blk & 127) * 4;
    const int wid = threadIdx.x >> 6, lane = threadIdx.x & 63;
    const int vox = vox0 + wid;
    const int r = (n*3 + sn)*512 + vox;       // pred row
    const float* hv = h + (size_t)((n*7 + sn + 4)*512 + vox)*64;

    // phase 1 (per wave): y = hv @ w1 + b1, LN, gelu
    float yv = b1[lane];
    for (int k = 0; k < 64; ++k) yv = fmaf(hv[k], w1[k*64 + lane], yv);
    float mu = wred_sum(yv) * (1.f/64.f);
    float d = yv - mu;
    float var = wred_sum(d*d) * (1.f/64.f);
    float ln = d * rsqrtf(var + 1e-5f) * lng[lane] + lnb[lane];
    zv[wid][lane] = 0.5f * ln * (1.f + erff(ln * 0.70710678118654752f));

    // phase 2 (per wave, same-wave LDS reuse): 8 couts per lane
    float l[8];
    #pragma unroll
    for (int j = 0; j < 8; ++j) l[j] = b2[j*64 + lane];
    for (int k = 0; k < 64; ++k) {
        float zz = zv[wid][k];
        #pragma unroll
        for (int j = 0; j < 8; ++j)
            l[j] = fmaf(zz, w2[k*512 + j*64 + lane], l[j]);
    }
    #pragma unroll
    for (int j = 0; j < 8; ++j) lg[wid][j*64 + lane] = l[j];

    // argmax (first-max tiebreak) + softmax denom, per wave
    float m = l[0]; int mi = lane;
    #pragma unroll
    for (int j = 1; j < 8; ++j)
        if (l[j] > m) { m = l[j]; mi = j*64 + lane; }
    #pragma unroll
    for (int o = 32; o > 0; o >>= 1) {
        float om = __shfl_down(m, o, 64);
        int   oi = __shfl_down(mi, o, 64);
        if (om > m || (om == m && oi < mi)) { m = om; mi = oi; }
    }
    float maxv = __shfl(m, 0, 64);
    int   maxi = __shfl(mi, 0, 64);
    float es = 0.f;
    #pragma unroll
    for (int j = 0; j < 8; ++j) es += expf(l[j] - maxv);
    float sum = wred_sum(es);
    if (lane == 0) {
        int target = ncode[(n*3 + sn)*512 + vox];
        float logp = lg[wid][target] - maxv - logf(sum);
        atomicAdd(out + 1572864, -logp * (1.f/3072.f));
        out[1572865 + r] = (float)maxi;
    }

    // score write: transpose through LDS -> coalesced float4 on vox
    __syncthreads();
    const int t = threadIdx.x;
    #pragma unroll
    for (int jj = 0; jj < 2; ++jj) {
        int co = t + jj*256;
        float4 o4 = { lg[0][co], lg[1][co], lg[2][co], lg[3][co] };
        *(float4*)(out + (size_t)((n*512 + co)*3 + sn)*512 + vox0) = o4;
    }
}

extern "C" void kernel_launch(void* const* d_in, const int* in_sizes, int n_in,
                              void* d_out, int out_size, void* d_ws, size_t ws_size,
                              hipStream_t stream) {
    (void)in_sizes; (void)n_in; (void)out_size; (void)ws_size;
    const int*   code  = (const int*)d_in[0];
    const int*   ncode = (const int*)d_in[1];
    const float* emb   = (const float*)d_in[2];
    const float* win   = (const float*)d_in[3];
    const float* bin_  = (const float*)d_in[4];
    const float* gin_w = (const float*)d_in[5];
    const float* gin_b = (const float*)d_in[6];
    const float* wh    = (const float*)d_in[7];
    const float* bh    = (const float*)d_in[8];
    const float* gh_w  = (const float*)d_in[9];
    const float* gh_b  = (const float*)d_in[10];
    const float* w1    = (const float*)d_in[11];
    const float* b1    = (const float*)d_in[12];
    const float* ln_g  = (const float*)d_in[13];
    const float* ln_b  = (const float*)d_in[14];
    const float* w2    = (const float*)d_in[15];
    const float* b2    = (const float*)d_in[16];
    float* out = (float*)d_out;

    float* h    = (float*)d_ws;        // [2][7][512][64]   = 458752
    float* gi   = h + 458752;          // [2][7][512][256]  = 1835008
    float* ghat = gi + 1835008;        // [2][512][256]     = 262144
    float* hx   = ghat + 262144;       // [2][512][64]      = 65536
    float* cx   = hx + 65536;          // [2][512][64]      = 65536

    hipMemsetAsync(out + 1572864, 0, sizeof(float), stream);   // loss accumulator
    embed_kernel<<<1792, 256, 0, stream>>>(code, ncode, emb, h);

    for (int l = 0; l < 2; ++l) {
        conv_kernel<<<14*32, 256, 0, stream>>>(h, win + l*WSTRIDE, bin_ + l*256, gi);
        ln_kernel<<<1792, 256, 0, stream>>>(gi, gin_w + l*256, gin_b + l*256);
        hipMemsetAsync(hx, 0, 65536*sizeof(float), stream);
        hipMemsetAsync(cx, 0, 65536*sizeof(float), stream);
        for (int s = 0; s < 7; ++s) {
            conv_rec_kernel<<<256, 256, 0, stream>>>(hx, wh + l*WSTRIDE, bh + l*256, ghat);
            gates_kernel<<<256, 256, 0, stream>>>(ghat, gi, gh_w + l*256, gh_b + l*256,
                                                  hx, cx, h, s);
        }
    }
    head_kernel<<<768, 256, 0, stream>>>(h, w1, b1, ln_g, ln_b, w2, b2, ncode, out);
}